// Round 10
// baseline (196.823 us; speedup 1.0000x reference)
//
#include <hip/hip_runtime.h>
#include <hip/hip_bf16.h>
#include <math.h>

#define N_SEQ 4096
#define DIM   1024
#define NHEAD 16
#define HDIM  64
#define E3    3072

typedef short bf16x8 __attribute__((ext_vector_type(8)));
typedef float f32x4  __attribute__((ext_vector_type(4)));
typedef unsigned int u32;

#if __has_builtin(__builtin_amdgcn_exp2f)
#define EXP2(x) __builtin_amdgcn_exp2f(x)   // raw v_exp_f32; exp2(-inf)=0
#else
#define EXP2(x) exp2f(x)
#endif

__device__ __forceinline__ float bf2f(unsigned short u) {
    union { unsigned int i; float f; } x; x.i = ((unsigned int)u) << 16; return x.f;
}
__device__ __forceinline__ unsigned short f2bf(float f) {
    union { float f; unsigned int i; } x; x.f = f;
    unsigned int r = x.i + 0x7FFF + ((x.i >> 16) & 1);   // round-to-nearest-even
    return (unsigned short)(r >> 16);
}
// cheap pack for non-negative hot-loop values (round-half-up, 2 VALU ops)
__device__ __forceinline__ unsigned short f2bf_fast(float f) {
    union { float f; unsigned int i; } x; x.f = f;
    return (unsigned short)((x.i + 0x8000u) >> 16);
}
__device__ __forceinline__ f32x4 mfma16(bf16x8 a, bf16x8 b, f32x4 c) {
    return __builtin_amdgcn_mfma_f32_16x16x32_bf16(a, b, c, 0, 0, 0);
}
// async global->LDS, 16B per lane; LDS dest = wave-uniform base + lane*16
__device__ __forceinline__ void gload_lds16(const unsigned short* g, unsigned short* l) {
    __builtin_amdgcn_global_load_lds(
        (const __attribute__((address_space(1))) u32*)g,
        (__attribute__((address_space(3))) u32*)l, 16, 0, 0);
}

// local (per-block) dtype probe
__device__ __forceinline__ int probe_isf32(const unsigned short* __restrict__ X) {
    __shared__ int cnt;
    if (threadIdx.x == 0) cnt = 0;
    __syncthreads();
    int bad = 0;
    for (int i = threadIdx.x; i < 4096; i += 256) {
        float v = bf2f(X[i]);
        if (!(fabsf(v) < 1e10f)) bad = 1;
    }
    if (bad) atomicAdd(&cnt, 1);
    __syncthreads();
    return cnt > 0;
}

// ---------------------------------------------------------------------------
// Kernel 0: fused prep: RoPE cos/sin table (always) + local dtype detect,
// convert only if fp32.  Table: Rt[n*16+f] = (cos(n*w_f), cos(n*w_{f+16}),
// sin(n*w_f), sin(n*w_{f+16})).
// ---------------------------------------------------------------------------
__global__ __launch_bounds__(256)
void prep_kernel(const void* __restrict__ X, const void* __restrict__ Wq,
                 const void* __restrict__ Wo,
                 unsigned short* __restrict__ Xb, unsigned short* __restrict__ Wqb,
                 unsigned short* __restrict__ Wob,
                 float4* __restrict__ Rt,
                 int* __restrict__ flag)
{
    // RoPE table fill (independent of dtype probe)
    const int ti = blockIdx.x * blockDim.x + threadIdx.x;
    if (ti < N_SEQ * 16) {
        const int n = ti >> 4, f = ti & 15;
        const float i0 = powf(10000.f, -((float)f)        * (1.f/32.f));
        const float i1 = powf(10000.f, -((float)(f + 16)) * (1.f/32.f));
        float s0, c0, s1, c1;
        sincosf((float)n * i0, &s0, &c0);
        sincosf((float)n * i1, &s1, &c1);
        Rt[ti] = (float4){c0, c1, s0, s1};
    }

    const int isf32 = probe_isf32((const unsigned short*)X);
    if (blockIdx.x == 0 && threadIdx.x == 0) *flag = isf32;
    if (!isf32) return;

    const int nX4  = (N_SEQ * DIM) >> 2;
    const int nWq4 = (E3 * DIM) >> 2;
    const int nWo4 = (DIM * DIM) >> 2;
    const int total = nX4 + nWq4 + nWo4;
    const int stride = gridDim.x * blockDim.x;
    for (int i = blockIdx.x * blockDim.x + threadIdx.x; i < total; i += stride) {
        const float4* src; ushort4* dst; int j = i;
        if (j < nX4)                { src = (const float4*)X  + j;  dst = (ushort4*)Xb  + j; }
        else if ((j -= nX4) < nWq4) { src = (const float4*)Wq + j;  dst = (ushort4*)Wqb + j; }
        else { j -= nWq4;             src = (const float4*)Wo + j;  dst = (ushort4*)Wob + j; }
        float4 v = *src;
        ushort4 u;
        u.x = f2bf(v.x); u.y = f2bf(v.y); u.z = f2bf(v.z); u.w = f2bf(v.w);
        *dst = u;
    }
}

// ---------------------------------------------------------------------------
// Kernel 1: QKV projection + fused RoPE (r11-proven main loop; epilogue reads
// the precomputed RoPE table — frozen from r3).
// ---------------------------------------------------------------------------
__global__ __launch_bounds__(256)
void qkv_mfma_kernel(const void* __restrict__ Xo, const unsigned short* __restrict__ Xc,
                     const void* __restrict__ Wo_, const unsigned short* __restrict__ Wc,
                     const int* __restrict__ flag,
                     const float4* __restrict__ Rt,
                     unsigned short* __restrict__ Qf,
                     unsigned short* __restrict__ Kf,
                     unsigned short* __restrict__ Vf)
{
    __shared__ __align__(16) unsigned short SMEM[4][4096];   // 32 KB

    const int isf32 = *flag;
    const unsigned short* Xb = isf32 ? Xc : (const unsigned short*)Xo;
    const unsigned short* Wb = isf32 ? Wc : (const unsigned short*)Wo_;

    const int tid  = threadIdx.x;
    const int lane = tid & 63;
    const int wave = tid >> 6;
    const int wr = wave >> 1, wc = wave & 1;
    const int lm = lane & 15, q4 = lane >> 4;
    const int rbase = blockIdx.y * 128;   // n
    const int cbase = blockIdx.x * 128;   // e

    const int srow = wave * 16 + (lane >> 2);
    const int scol = (lane & 3) * 8;

    const unsigned short* xsrc = Xb + (size_t)(rbase + srow) * DIM + scol;
    const unsigned short* wsrc = Wb + (size_t)(cbase + srow) * DIM + scol;
    const int la = (wr*64 + lm)*32 + q4*8;
    const int lb = (wc*64 + lm)*32 + q4*8;

    f32x4 acc[4][4];
    #pragma unroll
    for (int i = 0; i < 4; ++i)
        #pragma unroll
        for (int j = 0; j < 4; ++j) acc[i][j] = (f32x4){0.f, 0.f, 0.f, 0.f};

    #define QSTAGE(buf)                                                             \
        {                                                                           \
            _Pragma("unroll")                                                       \
            for (int j = 0; j < 2; ++j) {                                           \
                gload_lds16(xsrc + (size_t)j*64*DIM, &SMEM[buf][j*2048 + wave*512]);   \
                gload_lds16(wsrc + (size_t)j*64*DIM, &SMEM[2+buf][j*2048 + wave*512]); \
            }                                                                       \
            xsrc += 32; wsrc += 32;                                                 \
        }

    QSTAGE(0)
    for (int it = 0; it < DIM/32; ++it) {
        const int cur = it & 1;
        __syncthreads();
        if (it + 1 < DIM/32) QSTAGE(cur ^ 1)

        bf16x8 a[4], b[4];
        #pragma unroll
        for (int mi = 0; mi < 4; ++mi)
            a[mi] = *(const bf16x8*)&SMEM[cur][la + mi*512];
        #pragma unroll
        for (int ni = 0; ni < 4; ++ni)
            b[ni] = *(const bf16x8*)&SMEM[2+cur][lb + ni*512];
        #pragma unroll
        for (int mi = 0; mi < 4; ++mi)
            #pragma unroll
            for (int ni = 0; ni < 4; ++ni)
                acc[mi][ni] = mfma16(a[mi], b[ni], acc[mi][ni]);
    }
    #undef QSTAGE

    __syncthreads();   // staging LDS now free for epilogue transpose

    const int ecol = cbase + wc * 64;
    const int part = ecol >> 10;            // 0=q, 1=k, 2=v
    const int h    = (ecol >> 6) & 15;
    unsigned short* ep = &SMEM[0][0] + wave*4096;

    if (part == 2) {
        #pragma unroll
        for (int mh = 0; mh < 2; ++mh) {
            #pragma unroll
            for (int mi2 = 0; mi2 < 2; ++mi2) {
                const int mi = mh*2 + mi2;
                #pragma unroll
                for (int r = 0; r < 4; ++r) {
                    const int n31 = mi2*16 + q4*4 + r;
                    #pragma unroll
                    for (int ni = 0; ni < 4; ++ni)
                        ep[(ni*16 + lm)*40 + n31] = f2bf(acc[mi][ni][r]);
                }
            }
            const int nb = rbase + wr*64 + mh*32;
            const size_t vb = (((size_t)h*128 + (nb >> 5)) << 11) + (size_t)lane*8;
            #pragma unroll
            for (int ni = 0; ni < 4; ++ni) {
                const bf16x8 fr = *(const bf16x8*)(ep + (ni*16 + lm)*40 + q4*8);
                *(bf16x8*)(Vf + vb + (size_t)ni*512) = fr;
            }
        }
    } else {
        unsigned short* dst = (part == 0) ? Qf : Kf;
        const float scl = (part == 0) ? 0.180336884f : 1.0f;   // log2(e)/8 folded into Q
        #pragma unroll
        for (int mi = 0; mi < 4; ++mi) {
            const int tn = rbase + wr*64 + mi*16;
            #pragma unroll
            for (int r = 0; r < 4; ++r) {
                const int n = tn + q4*4 + r;
                const float4 t = Rt[(n << 4) + lm];   // c0, c1, s0, s1 (coalesced 16B)
                const int row = (q4*4 + r)*72;
                ep[row + lm]      = f2bf((acc[mi][0][r]*t.x - acc[mi][2][r]*t.z) * scl);
                ep[row + lm + 16] = f2bf((acc[mi][1][r]*t.y - acc[mi][3][r]*t.w) * scl);
                ep[row + lm + 32] = f2bf((acc[mi][2][r]*t.x + acc[mi][0][r]*t.z) * scl);
                ep[row + lm + 48] = f2bf((acc[mi][3][r]*t.y + acc[mi][1][r]*t.w) * scl);
            }
            const size_t tb = (((size_t)(h*256 + (tn >> 4))) << 10) + (size_t)lane*8;
            #pragma unroll
            for (int c = 0; c < 2; ++c) {
                const bf16x8 fr = *(const bf16x8*)(ep + lm*72 + c*32 + q4*8);
                *(bf16x8*)(dst + tb + (size_t)c*512) = fr;
            }
        }
    }
}

// ---------------------------------------------------------------------------
// Kernel 2: MFMA flash attention — EXACT R3 structure (54.5 us best: 4 waves,
// paired streams A=p/B=63-p sharing K/V loads, direct-L2 reads, barrier-free
// loop, K reg-dbuf, early V issue, p = blockIdx>>4 LPT order).  R9's
// complementary remap REVERTED (60.3 us: static co-residency model false).
// Single new lever: s_setprio(1) around the two MFMA clusters only (T5,
// m191 attn regime +4-7%) — isolates the half of R4's bundle that was
// never attributed.  Prio drops to 0 for the exp/pack VALU phase so
// out-of-phase waves' MFMAs can claim the matrix pipe.
// ---------------------------------------------------------------------------
__global__ __launch_bounds__(256, 2)
void attn_mfma_kernel(const unsigned short* __restrict__ Qf,
                      const unsigned short* __restrict__ Kf,
                      const unsigned short* __restrict__ Vf,
                      unsigned short* __restrict__ Attn)
{
    __shared__ __align__(16) unsigned short P16[4][2][32][40];  // 20 KB [wave][stream]
    __shared__ __align__(16) float Ox[2][32][64];               // 16 KB (A then B)
    __shared__ float Lx[2][32];

    const int tid  = threadIdx.x;
    const int lane = tid & 63;
    const int wave = tid >> 6;
    const int q4 = lane >> 4, lm = lane & 15;
    const int qh = wave >> 1, kh = wave & 1;

    const int h = blockIdx.x & 15;          // head h -> XCD h%8 (L2-resident K/V)
    const int p = blockIdx.x >> 4;          // pair index 0..31 (LPT order, r3-proven)
    const int qwA = (p << 6) + (qh << 5);          // stream A: query block p
    const int qwB = ((63 - p) << 6) + (qh << 5);   // stream B: query block 63-p
    const int ntA = p + 1;
    const int ntB = 64 - p;

    // Q A-frags for both streams: [qi][d-chunk]
    const unsigned short* qpA = Qf + (((size_t)(h*256 + (qwA >> 4))) << 10) + (size_t)lane * 8;
    const unsigned short* qpB = Qf + (((size_t)(h*256 + (qwB >> 4))) << 10) + (size_t)lane * 8;
    bf16x8 aqA[2][2], aqB[2][2];
    #pragma unroll
    for (int qi = 0; qi < 2; ++qi)
        #pragma unroll
        for (int d = 0; d < 2; ++d) {
            aqA[qi][d] = *(const bf16x8*)(qpA + qi*1024 + d*512);
            aqB[qi][d] = *(const bf16x8*)(qpB + qi*1024 + d*512);
        }

    float lA[2][4], lB[2][4];
    f32x4 oA[2][4], oB[2][4];
    #pragma unroll
    for (int qi = 0; qi < 2; ++qi) {
        #pragma unroll
        for (int r = 0; r < 4; ++r) { lA[qi][r] = 0.f; lB[qi][r] = 0.f; }
        #pragma unroll
        for (int dc = 0; dc < 4; ++dc) {
            oA[qi][dc] = (f32x4){0.f, 0.f, 0.f, 0.f};
            oB[qi][dc] = (f32x4){0.f, 0.f, 0.f, 0.f};
        }
    }

    // direct-global fragment pointers (this wave's 32-key half of each tile)
    const size_t hb = ((size_t)h) << 18;
    const unsigned short* kc = Kf + hb + (size_t)(kh*2048) + (size_t)lane*8;
    const unsigned short* vc = Vf + hb + (size_t)(kh*2048) + (size_t)lane*8;

    unsigned short* pwA  = &P16[wave][0][0][0];
    unsigned short* pwB  = &P16[wave][1][0][0];
    unsigned short* pwaA = pwA + (4*q4)*40 + lm;       // + qi*640 + r*40 + ki*16
    unsigned short* pwaB = pwB + (4*q4)*40 + lm;
    const unsigned short* parA = pwA + lm*40 + q4*8;   // + qi*640
    const unsigned short* parB = pwB + lm*40 + q4*8;

    // K register double-buffer: preload tile 0
    bf16x8 bk[2][2];
    bk[0][0] = *(const bf16x8*)(kc);
    bk[0][1] = *(const bf16x8*)(kc + 512);
    bk[1][0] = *(const bf16x8*)(kc + 1024);
    bk[1][1] = *(const bf16x8*)(kc + 1536);

    for (int it = 0; it < ntB; ++it) {
        const int kt = it << 6;
        const int doA = (it < ntA);         // wave-uniform

        // V frags for this tile: issue early, use after exp/P phase
        bf16x8 bv[4];
        #pragma unroll
        for (int dc = 0; dc < 4; ++dc)
            bv[dc] = *(const bf16x8*)(vc + dc*512);

        // prefetch next K tile (overshoot lands in adjacent workspace, never used)
        bf16x8 nk[2][2];
        nk[0][0] = *(const bf16x8*)(kc + 4096);
        nk[0][1] = *(const bf16x8*)(kc + 4096 + 512);
        nk[1][0] = *(const bf16x8*)(kc + 4096 + 1024);
        nk[1][1] = *(const bf16x8*)(kc + 4096 + 1536);

        // ---- S = Q K^T for both streams (independent chains) ----
        __builtin_amdgcn_s_setprio(1);
        f32x4 sB[2][2], sA[2][2];
        #pragma unroll
        for (int ki = 0; ki < 2; ++ki)
            #pragma unroll
            for (int qi = 0; qi < 2; ++qi) {
                f32x4 z = (f32x4){0.f, 0.f, 0.f, 0.f};
                z = mfma16(aqB[qi][0], bk[ki][0], z);
                sB[qi][ki] = mfma16(aqB[qi][1], bk[ki][1], z);
            }
        if (doA) {
            #pragma unroll
            for (int ki = 0; ki < 2; ++ki)
                #pragma unroll
                for (int qi = 0; qi < 2; ++qi) {
                    f32x4 z = (f32x4){0.f, 0.f, 0.f, 0.f};
                    z = mfma16(aqA[qi][0], bk[ki][0], z);
                    sA[qi][ki] = mfma16(aqA[qi][1], bk[ki][1], z);
                }
        }
        __builtin_amdgcn_s_setprio(0);

        // ---- causal mask (only fires on each stream's last tiles) ----
        if (kt + 32*kh + 31 > qwB) {
            #pragma unroll
            for (int ki = 0; ki < 2; ++ki) {
                const int key = kt + 32*kh + 16*ki + lm;
                #pragma unroll
                for (int qi = 0; qi < 2; ++qi) {
                    const int qq = qwB + 16*qi + 4*q4;
                    #pragma unroll
                    for (int r = 0; r < 4; ++r)
                        if (key > qq + r) sB[qi][ki][r] = -INFINITY;
                }
            }
        }

        // ---- p = exp2(s); l accumulate; P write (per-wave LDS, no barrier) ----
        #pragma unroll
        for (int qi = 0; qi < 2; ++qi)
            #pragma unroll
            for (int ki = 0; ki < 2; ++ki)
                #pragma unroll
                for (int r = 0; r < 4; ++r) {
                    const float pb = EXP2(sB[qi][ki][r]);
                    lB[qi][r] += pb;
                    pwaB[qi*640 + r*40 + ki*16] = f2bf_fast(pb);
                }

        if (doA) {
            if (kt + 32*kh + 31 > qwA) {
                #pragma unroll
                for (int ki = 0; ki < 2; ++ki) {
                    const int key = kt + 32*kh + 16*ki + lm;
                    #pragma unroll
                    for (int qi = 0; qi < 2; ++qi) {
                        const int qq = qwA + 16*qi + 4*q4;
                        #pragma unroll
                        for (int r = 0; r < 4; ++r)
                            if (key > qq + r) sA[qi][ki][r] = -INFINITY;
                    }
                }
            }
            #pragma unroll
            for (int qi = 0; qi < 2; ++qi)
                #pragma unroll
                for (int ki = 0; ki < 2; ++ki)
                    #pragma unroll
                    for (int r = 0; r < 4; ++r) {
                        const float pa = EXP2(sA[qi][ki][r]);
                        lA[qi][r] += pa;
                        pwaA[qi*640 + r*40 + ki*16] = f2bf_fast(pa);
                    }
        }

        // ---- O += P V for both streams ----
        __builtin_amdgcn_s_setprio(1);
        {
            bf16x8 paB[2];
            paB[0] = *(const bf16x8*)(parB);
            paB[1] = *(const bf16x8*)(parB + 640);
            #pragma unroll
            for (int dc = 0; dc < 4; ++dc)
                #pragma unroll
                for (int qi = 0; qi < 2; ++qi)
                    oB[qi][dc] = mfma16(paB[qi], bv[dc], oB[qi][dc]);
        }
        if (doA) {
            bf16x8 paA[2];
            paA[0] = *(const bf16x8*)(parA);
            paA[1] = *(const bf16x8*)(parA + 640);
            #pragma unroll
            for (int dc = 0; dc < 4; ++dc)
                #pragma unroll
                for (int qi = 0; qi < 2; ++qi)
                    oA[qi][dc] = mfma16(paA[qi], bv[dc], oA[qi][dc]);
        }
        __builtin_amdgcn_s_setprio(0);

        kc += 4096; vc += 4096;
        bk[0][0] = nk[0][0]; bk[0][1] = nk[0][1];
        bk[1][0] = nk[1][0]; bk[1][1] = nk[1][1];
    }

    // ---- l reduction over the key axis within the wave (lm groups) ----
    #pragma unroll
    for (int qi = 0; qi < 2; ++qi)
        #pragma unroll
        for (int r = 0; r < 4; ++r) {
            float a = lA[qi][r], b = lB[qi][r];
            #pragma unroll
            for (int mk = 1; mk <= 8; mk <<= 1) {
                a += __shfl_xor(a, mk);
                b += __shfl_xor(b, mk);
            }
            lA[qi][r] = a; lB[qi][r] = b;
        }

    // ---- cross-wave (key-half) reduction: stream A, then stream B ----
    if (kh == 1) {
        #pragma unroll
        for (int qi = 0; qi < 2; ++qi)
            #pragma unroll
            for (int r = 0; r < 4; ++r) {
                const int qq = 16*qi + 4*q4 + r;
                #pragma unroll
                for (int dc = 0; dc < 4; ++dc)
                    Ox[qh][qq][16*dc + lm] = oA[qi][dc][r];
                if (lm == 0) Lx[qh][qq] = lA[qi][r];
            }
    }
    __syncthreads();
    if (kh == 0) {
        #pragma unroll
        for (int qi = 0; qi < 2; ++qi)
            #pragma unroll
            for (int r = 0; r < 4; ++r) {
                const int qq = 16*qi + 4*q4 + r;
                const float inv = 1.f / (lA[qi][r] + Lx[qh][qq]);
                const size_t row = (size_t)(qwA + qq) * DIM + (h << 6) + lm;
                #pragma unroll
                for (int dc = 0; dc < 4; ++dc) {
                    const float v = oA[qi][dc][r] + Ox[qh][qq][16*dc + lm];
                    Attn[row + 16*dc] = f2bf(v * inv);
                }
            }
    }
    __syncthreads();
    if (kh == 1) {
        #pragma unroll
        for (int qi = 0; qi < 2; ++qi)
            #pragma unroll
            for (int r = 0; r < 4; ++r) {
                const int qq = 16*qi + 4*q4 + r;
                #pragma unroll
                for (int dc = 0; dc < 4; ++dc)
                    Ox[qh][qq][16*dc + lm] = oB[qi][dc][r];
                if (lm == 0) Lx[qh][qq] = lB[qi][r];
            }
    }
    __syncthreads();
    if (kh == 0) {
        #pragma unroll
        for (int qi = 0; qi < 2; ++qi)
            #pragma unroll
            for (int r = 0; r < 4; ++r) {
                const int qq = 16*qi + 4*q4 + r;
                const float inv = 1.f / (lB[qi][r] + Lx[qh][qq]);
                const size_t row = (size_t)(qwB + qq) * DIM + (h << 6) + lm;
                #pragma unroll
                for (int dc = 0; dc < 4; ++dc) {
                    const float v = oB[qi][dc][r] + Ox[qh][qq][16*dc + lm];
                    Attn[row + 16*dc] = f2bf(v * inv);
                }
            }
    }
}

// ---------------------------------------------------------------------------
// Kernel 3: out projection, MFMA, 128x64 tiles + dbuf staging (r10-proven).
// ---------------------------------------------------------------------------
__global__ __launch_bounds__(256)
void out_mfma_kernel(const unsigned short* __restrict__ Ab,
                     const void* __restrict__ Wo_, const unsigned short* __restrict__ Wc,
                     const int* __restrict__ flag,
                     void* __restrict__ Out)
{
    __shared__ unsigned short As[2][4096];   // 16 KB
    __shared__ unsigned short Bs[2][2048];   // 8 KB

    const int isf32 = *flag;
    const unsigned short* Wb = isf32 ? Wc : (const unsigned short*)Wo_;

    const int tid  = threadIdx.x;
    const int lane = tid & 63;
    const int wave = tid >> 6;
    const int lm = lane & 15, q4 = lane >> 4;
    const int rbase = blockIdx.y * 128;
    const int cbase = blockIdx.x * 64;

    const int srow16 = lane >> 2;
    const int scol = (lane & 3) * 8;

    const unsigned short* asrc = Ab + (size_t)(rbase + wave*32 + srow16) * DIM + scol;
    const unsigned short* bsrc = Wb + (size_t)(cbase + wave*16 + srow16) * DIM + scol;
    const int la = (wave*32 + lm)*32 + q4*8;
    const int lb = lm*32 + q4*8;

    f32x4 acc[2][4];
    #pragma unroll
    for (int i = 0; i < 2; ++i)
        #pragma unroll
        for (int j = 0; j < 4; ++j) acc[i][j] = (f32x4){0.f, 0.f, 0.f, 0.f};

    #define OSTAGE(buf)                                                          \
        {                                                                        \
            _Pragma("unroll")                                                    \
            for (int j = 0; j < 2; ++j)                                          \
                gload_lds16(asrc + (size_t)j*16*DIM, &As[buf][(wave*32 + j*16)*32]); \
            gload_lds16(bsrc, &Bs[buf][(wave*16)*32]);                           \
            asrc += 32; bsrc += 32;                                              \
        }

    OSTAGE(0)
    for (int it = 0; it < DIM/32; ++it) {
        const int cur = it & 1;
        __syncthreads();
        if (it + 1 < DIM/32) OSTAGE(cur ^ 1)

        bf16x8 a[2], b[4];
        #pragma unroll
        for (int mi = 0; mi < 2; ++mi)
            a[mi] = *(const bf16x8*)&As[cur][la + mi*512];
        #pragma unroll
        for (int ni = 0; ni < 4; ++ni)
            b[ni] = *(const bf16x8*)&Bs[cur][lb + ni*512];
        #pragma unroll
        for (int mi = 0; mi < 2; ++mi)
            #pragma unroll
            for (int ni = 0; ni < 4; ++ni)
                acc[mi][ni] = mfma16(a[mi], b[ni], acc[mi][ni]);
    }
    #undef OSTAGE

    #pragma unroll
    for (int mi = 0; mi < 2; ++mi)
        #pragma unroll
        for (int r = 0; r < 4; ++r) {
            const size_t n = rbase + wave*32 + mi*16 + q4*4 + r;
            #pragma unroll
            for (int ni = 0; ni < 4; ++ni) {
                const size_t e = cbase + ni*16 + lm;
                const float v = acc[mi][ni][r];
                if (isf32) ((float*)Out)[n * DIM + e] = v;
                else       ((unsigned short*)Out)[n * DIM + e] = f2bf(v);
            }
        }
}

// ---------------------------------------------------------------------------
extern "C" void kernel_launch(void* const* d_in, const int* in_sizes, int n_in,
                              void* d_out, int out_size, void* d_ws, size_t ws_size,
                              hipStream_t stream) {
    const void* X    = d_in[0];
    const void* Wqkv = d_in[1];
    const void* Wout = d_in[2];

    int* flag = (int*)d_ws;
    unsigned short* base = (unsigned short*)((char*)d_ws + 256);
    const size_t nX = (size_t)N_SEQ * DIM;
    const size_t nWq = (size_t)E3 * DIM;
    const size_t nWo = (size_t)DIM * DIM;
    unsigned short* Xb  = base;
    unsigned short* Wqb = Xb + nX;
    unsigned short* Wob = Wqb + nWq;
    unsigned short* Qf  = Wob + nWo;
    unsigned short* Kf  = Qf + nX;
    unsigned short* Vf  = Kf + nX;
    unsigned short* At  = Vf + nX;
    float4* Rt = (float4*)(At + nX);     // RoPE table: 4096*16 float4 = 1 MB

    prep_kernel<<<768, 256, 0, stream>>>(X, Wqkv, Wout, Xb, Wqb, Wob, Rt, flag);
    qkv_mfma_kernel<<<dim3(E3 / 128, N_SEQ / 128), 256, 0, stream>>>(X, Xb, Wqkv, Wqb, flag, Rt, Qf, Kf, Vf);
    attn_mfma_kernel<<<dim3(NHEAD * 32), 256, 0, stream>>>(Qf, Kf, Vf, At);
    out_mfma_kernel<<<dim3(DIM / 64, N_SEQ / 128), 256, 0, stream>>>(At, Wout, Wob, flag, d_out);
}

// Round 11
// 192.713 us; speedup vs baseline: 1.0213x; 1.0213x over previous
//
#include <hip/hip_runtime.h>
#include <hip/hip_bf16.h>
#include <math.h>

#define N_SEQ 4096
#define DIM   1024
#define NHEAD 16
#define HDIM  64
#define E3    3072

typedef short bf16x8 __attribute__((ext_vector_type(8)));
typedef float f32x4  __attribute__((ext_vector_type(4)));
typedef unsigned int u32;

#if __has_builtin(__builtin_amdgcn_exp2f)
#define EXP2(x) __builtin_amdgcn_exp2f(x)   // raw v_exp_f32; exp2(-inf)=0
#else
#define EXP2(x) exp2f(x)
#endif

__device__ __forceinline__ float bf2f(unsigned short u) {
    union { unsigned int i; float f; } x; x.i = ((unsigned int)u) << 16; return x.f;
}
__device__ __forceinline__ unsigned short f2bf(float f) {
    union { float f; unsigned int i; } x; x.f = f;
    unsigned int r = x.i + 0x7FFF + ((x.i >> 16) & 1);   // round-to-nearest-even
    return (unsigned short)(r >> 16);
}
// cheap pack for non-negative hot-loop values (round-half-up, 2 VALU ops)
__device__ __forceinline__ unsigned short f2bf_fast(float f) {
    union { float f; unsigned int i; } x; x.f = f;
    return (unsigned short)((x.i + 0x8000u) >> 16);
}
__device__ __forceinline__ f32x4 mfma16(bf16x8 a, bf16x8 b, f32x4 c) {
    return __builtin_amdgcn_mfma_f32_16x16x32_bf16(a, b, c, 0, 0, 0);
}
// async global->LDS, 16B per lane; LDS dest = wave-uniform base + lane*16
__device__ __forceinline__ void gload_lds16(const unsigned short* g, unsigned short* l) {
    __builtin_amdgcn_global_load_lds(
        (const __attribute__((address_space(1))) u32*)g,
        (__attribute__((address_space(3))) u32*)l, 16, 0, 0);
}

// local (per-block) dtype probe
__device__ __forceinline__ int probe_isf32(const unsigned short* __restrict__ X) {
    __shared__ int cnt;
    if (threadIdx.x == 0) cnt = 0;
    __syncthreads();
    int bad = 0;
    for (int i = threadIdx.x; i < 4096; i += 256) {
        float v = bf2f(X[i]);
        if (!(fabsf(v) < 1e10f)) bad = 1;
    }
    if (bad) atomicAdd(&cnt, 1);
    __syncthreads();
    return cnt > 0;
}

// ---------------------------------------------------------------------------
// Kernel 0: fused prep: RoPE cos/sin table (always) + local dtype detect,
// convert only if fp32.  Table: Rt[n*16+f] = (cos(n*w_f), cos(n*w_{f+16}),
// sin(n*w_f), sin(n*w_{f+16})).
// ---------------------------------------------------------------------------
__global__ __launch_bounds__(256)
void prep_kernel(const void* __restrict__ X, const void* __restrict__ Wq,
                 const void* __restrict__ Wo,
                 unsigned short* __restrict__ Xb, unsigned short* __restrict__ Wqb,
                 unsigned short* __restrict__ Wob,
                 float4* __restrict__ Rt,
                 int* __restrict__ flag)
{
    // RoPE table fill (independent of dtype probe)
    const int ti = blockIdx.x * blockDim.x + threadIdx.x;
    if (ti < N_SEQ * 16) {
        const int n = ti >> 4, f = ti & 15;
        const float i0 = powf(10000.f, -((float)f)        * (1.f/32.f));
        const float i1 = powf(10000.f, -((float)(f + 16)) * (1.f/32.f));
        float s0, c0, s1, c1;
        sincosf((float)n * i0, &s0, &c0);
        sincosf((float)n * i1, &s1, &c1);
        Rt[ti] = (float4){c0, c1, s0, s1};
    }

    const int isf32 = probe_isf32((const unsigned short*)X);
    if (blockIdx.x == 0 && threadIdx.x == 0) *flag = isf32;
    if (!isf32) return;

    const int nX4  = (N_SEQ * DIM) >> 2;
    const int nWq4 = (E3 * DIM) >> 2;
    const int nWo4 = (DIM * DIM) >> 2;
    const int total = nX4 + nWq4 + nWo4;
    const int stride = gridDim.x * blockDim.x;
    for (int i = blockIdx.x * blockDim.x + threadIdx.x; i < total; i += stride) {
        const float4* src; ushort4* dst; int j = i;
        if (j < nX4)                { src = (const float4*)X  + j;  dst = (ushort4*)Xb  + j; }
        else if ((j -= nX4) < nWq4) { src = (const float4*)Wq + j;  dst = (ushort4*)Wqb + j; }
        else { j -= nWq4;             src = (const float4*)Wo + j;  dst = (ushort4*)Wob + j; }
        float4 v = *src;
        ushort4 u;
        u.x = f2bf(v.x); u.y = f2bf(v.y); u.z = f2bf(v.z); u.w = f2bf(v.w);
        *dst = u;
    }
}

// ---------------------------------------------------------------------------
// Kernel 1: QKV projection + fused RoPE (r11-proven main loop; epilogue reads
// the precomputed RoPE table — frozen from r3).
// ---------------------------------------------------------------------------
__global__ __launch_bounds__(256)
void qkv_mfma_kernel(const void* __restrict__ Xo, const unsigned short* __restrict__ Xc,
                     const void* __restrict__ Wo_, const unsigned short* __restrict__ Wc,
                     const int* __restrict__ flag,
                     const float4* __restrict__ Rt,
                     unsigned short* __restrict__ Qf,
                     unsigned short* __restrict__ Kf,
                     unsigned short* __restrict__ Vf)
{
    __shared__ __align__(16) unsigned short SMEM[4][4096];   // 32 KB

    const int isf32 = *flag;
    const unsigned short* Xb = isf32 ? Xc : (const unsigned short*)Xo;
    const unsigned short* Wb = isf32 ? Wc : (const unsigned short*)Wo_;

    const int tid  = threadIdx.x;
    const int lane = tid & 63;
    const int wave = tid >> 6;
    const int wr = wave >> 1, wc = wave & 1;
    const int lm = lane & 15, q4 = lane >> 4;
    const int rbase = blockIdx.y * 128;   // n
    const int cbase = blockIdx.x * 128;   // e

    const int srow = wave * 16 + (lane >> 2);
    const int scol = (lane & 3) * 8;

    const unsigned short* xsrc = Xb + (size_t)(rbase + srow) * DIM + scol;
    const unsigned short* wsrc = Wb + (size_t)(cbase + srow) * DIM + scol;
    const int la = (wr*64 + lm)*32 + q4*8;
    const int lb = (wc*64 + lm)*32 + q4*8;

    f32x4 acc[4][4];
    #pragma unroll
    for (int i = 0; i < 4; ++i)
        #pragma unroll
        for (int j = 0; j < 4; ++j) acc[i][j] = (f32x4){0.f, 0.f, 0.f, 0.f};

    #define QSTAGE(buf)                                                             \
        {                                                                           \
            _Pragma("unroll")                                                       \
            for (int j = 0; j < 2; ++j) {                                           \
                gload_lds16(xsrc + (size_t)j*64*DIM, &SMEM[buf][j*2048 + wave*512]);   \
                gload_lds16(wsrc + (size_t)j*64*DIM, &SMEM[2+buf][j*2048 + wave*512]); \
            }                                                                       \
            xsrc += 32; wsrc += 32;                                                 \
        }

    QSTAGE(0)
    for (int it = 0; it < DIM/32; ++it) {
        const int cur = it & 1;
        __syncthreads();
        if (it + 1 < DIM/32) QSTAGE(cur ^ 1)

        bf16x8 a[4], b[4];
        #pragma unroll
        for (int mi = 0; mi < 4; ++mi)
            a[mi] = *(const bf16x8*)&SMEM[cur][la + mi*512];
        #pragma unroll
        for (int ni = 0; ni < 4; ++ni)
            b[ni] = *(const bf16x8*)&SMEM[2+cur][lb + ni*512];
        #pragma unroll
        for (int mi = 0; mi < 4; ++mi)
            #pragma unroll
            for (int ni = 0; ni < 4; ++ni)
                acc[mi][ni] = mfma16(a[mi], b[ni], acc[mi][ni]);
    }
    #undef QSTAGE

    __syncthreads();   // staging LDS now free for epilogue transpose

    const int ecol = cbase + wc * 64;
    const int part = ecol >> 10;            // 0=q, 1=k, 2=v
    const int h    = (ecol >> 6) & 15;
    unsigned short* ep = &SMEM[0][0] + wave*4096;

    if (part == 2) {
        #pragma unroll
        for (int mh = 0; mh < 2; ++mh) {
            #pragma unroll
            for (int mi2 = 0; mi2 < 2; ++mi2) {
                const int mi = mh*2 + mi2;
                #pragma unroll
                for (int r = 0; r < 4; ++r) {
                    const int n31 = mi2*16 + q4*4 + r;
                    #pragma unroll
                    for (int ni = 0; ni < 4; ++ni)
                        ep[(ni*16 + lm)*40 + n31] = f2bf(acc[mi][ni][r]);
                }
            }
            const int nb = rbase + wr*64 + mh*32;
            const size_t vb = (((size_t)h*128 + (nb >> 5)) << 11) + (size_t)lane*8;
            #pragma unroll
            for (int ni = 0; ni < 4; ++ni) {
                const bf16x8 fr = *(const bf16x8*)(ep + (ni*16 + lm)*40 + q4*8);
                *(bf16x8*)(Vf + vb + (size_t)ni*512) = fr;
            }
        }
    } else {
        unsigned short* dst = (part == 0) ? Qf : Kf;
        const float scl = (part == 0) ? 0.180336884f : 1.0f;   // log2(e)/8 folded into Q
        #pragma unroll
        for (int mi = 0; mi < 4; ++mi) {
            const int tn = rbase + wr*64 + mi*16;
            #pragma unroll
            for (int r = 0; r < 4; ++r) {
                const int n = tn + q4*4 + r;
                const float4 t = Rt[(n << 4) + lm];   // c0, c1, s0, s1 (coalesced 16B)
                const int row = (q4*4 + r)*72;
                ep[row + lm]      = f2bf((acc[mi][0][r]*t.x - acc[mi][2][r]*t.z) * scl);
                ep[row + lm + 16] = f2bf((acc[mi][1][r]*t.y - acc[mi][3][r]*t.w) * scl);
                ep[row + lm + 32] = f2bf((acc[mi][2][r]*t.x + acc[mi][0][r]*t.z) * scl);
                ep[row + lm + 48] = f2bf((acc[mi][3][r]*t.y + acc[mi][1][r]*t.w) * scl);
            }
            const size_t tb = (((size_t)(h*256 + (tn >> 4))) << 10) + (size_t)lane*8;
            #pragma unroll
            for (int c = 0; c < 2; ++c) {
                const bf16x8 fr = *(const bf16x8*)(ep + lm*72 + c*32 + q4*8);
                *(bf16x8*)(dst + tb + (size_t)c*512) = fr;
            }
        }
    }
}

// ---------------------------------------------------------------------------
// Kernel 2: MFMA flash attention — EXACT R3 structure, the measured best
// (54.5 us): 4 waves, paired streams A=p/B=63-p sharing K/V loads, direct-L2
// reads, barrier-free loop, K reg-dbuf, early V issue, LPT block order.
// Closed ledger: lagged-PV (r4, +5us), 8-wave splits (r5/r6, +14/+16us),
// LDS staging (r7, +40us), quad streams (r8, +9us), pair remap (r9, +6us),
// setprio (r10, +4us) ALL regressed.  This kernel is frozen.
// ---------------------------------------------------------------------------
__global__ __launch_bounds__(256, 2)
void attn_mfma_kernel(const unsigned short* __restrict__ Qf,
                      const unsigned short* __restrict__ Kf,
                      const unsigned short* __restrict__ Vf,
                      unsigned short* __restrict__ Attn)
{
    __shared__ __align__(16) unsigned short P16[4][2][32][40];  // 20 KB [wave][stream]
    __shared__ __align__(16) float Ox[2][32][64];               // 16 KB (A then B)
    __shared__ float Lx[2][32];

    const int tid  = threadIdx.x;
    const int lane = tid & 63;
    const int wave = tid >> 6;
    const int q4 = lane >> 4, lm = lane & 15;
    const int qh = wave >> 1, kh = wave & 1;

    const int h = blockIdx.x & 15;          // head h -> XCD h%8 (L2-resident K/V)
    const int p = blockIdx.x >> 4;          // pair index 0..31 (LPT order, r3-proven)
    const int qwA = (p << 6) + (qh << 5);          // stream A: query block p
    const int qwB = ((63 - p) << 6) + (qh << 5);   // stream B: query block 63-p
    const int ntA = p + 1;
    const int ntB = 64 - p;

    // Q A-frags for both streams: [qi][d-chunk]
    const unsigned short* qpA = Qf + (((size_t)(h*256 + (qwA >> 4))) << 10) + (size_t)lane * 8;
    const unsigned short* qpB = Qf + (((size_t)(h*256 + (qwB >> 4))) << 10) + (size_t)lane * 8;
    bf16x8 aqA[2][2], aqB[2][2];
    #pragma unroll
    for (int qi = 0; qi < 2; ++qi)
        #pragma unroll
        for (int d = 0; d < 2; ++d) {
            aqA[qi][d] = *(const bf16x8*)(qpA + qi*1024 + d*512);
            aqB[qi][d] = *(const bf16x8*)(qpB + qi*1024 + d*512);
        }

    float lA[2][4], lB[2][4];
    f32x4 oA[2][4], oB[2][4];
    #pragma unroll
    for (int qi = 0; qi < 2; ++qi) {
        #pragma unroll
        for (int r = 0; r < 4; ++r) { lA[qi][r] = 0.f; lB[qi][r] = 0.f; }
        #pragma unroll
        for (int dc = 0; dc < 4; ++dc) {
            oA[qi][dc] = (f32x4){0.f, 0.f, 0.f, 0.f};
            oB[qi][dc] = (f32x4){0.f, 0.f, 0.f, 0.f};
        }
    }

    // direct-global fragment pointers (this wave's 32-key half of each tile)
    const size_t hb = ((size_t)h) << 18;
    const unsigned short* kc = Kf + hb + (size_t)(kh*2048) + (size_t)lane*8;
    const unsigned short* vc = Vf + hb + (size_t)(kh*2048) + (size_t)lane*8;

    unsigned short* pwA  = &P16[wave][0][0][0];
    unsigned short* pwB  = &P16[wave][1][0][0];
    unsigned short* pwaA = pwA + (4*q4)*40 + lm;       // + qi*640 + r*40 + ki*16
    unsigned short* pwaB = pwB + (4*q4)*40 + lm;
    const unsigned short* parA = pwA + lm*40 + q4*8;   // + qi*640
    const unsigned short* parB = pwB + lm*40 + q4*8;

    // K register double-buffer: preload tile 0
    bf16x8 bk[2][2];
    bk[0][0] = *(const bf16x8*)(kc);
    bk[0][1] = *(const bf16x8*)(kc + 512);
    bk[1][0] = *(const bf16x8*)(kc + 1024);
    bk[1][1] = *(const bf16x8*)(kc + 1536);

    for (int it = 0; it < ntB; ++it) {
        const int kt = it << 6;
        const int doA = (it < ntA);         // wave-uniform

        // V frags for this tile: issue early, use after exp/P phase
        bf16x8 bv[4];
        #pragma unroll
        for (int dc = 0; dc < 4; ++dc)
            bv[dc] = *(const bf16x8*)(vc + dc*512);

        // prefetch next K tile (overshoot lands in adjacent workspace, never used)
        bf16x8 nk[2][2];
        nk[0][0] = *(const bf16x8*)(kc + 4096);
        nk[0][1] = *(const bf16x8*)(kc + 4096 + 512);
        nk[1][0] = *(const bf16x8*)(kc + 4096 + 1024);
        nk[1][1] = *(const bf16x8*)(kc + 4096 + 1536);

        // ---- S = Q K^T for both streams (independent chains) ----
        f32x4 sB[2][2], sA[2][2];
        #pragma unroll
        for (int ki = 0; ki < 2; ++ki)
            #pragma unroll
            for (int qi = 0; qi < 2; ++qi) {
                f32x4 z = (f32x4){0.f, 0.f, 0.f, 0.f};
                z = mfma16(aqB[qi][0], bk[ki][0], z);
                sB[qi][ki] = mfma16(aqB[qi][1], bk[ki][1], z);
            }
        if (doA) {
            #pragma unroll
            for (int ki = 0; ki < 2; ++ki)
                #pragma unroll
                for (int qi = 0; qi < 2; ++qi) {
                    f32x4 z = (f32x4){0.f, 0.f, 0.f, 0.f};
                    z = mfma16(aqA[qi][0], bk[ki][0], z);
                    sA[qi][ki] = mfma16(aqA[qi][1], bk[ki][1], z);
                }
        }

        // ---- causal mask (only fires on each stream's last tiles) ----
        if (kt + 32*kh + 31 > qwB) {
            #pragma unroll
            for (int ki = 0; ki < 2; ++ki) {
                const int key = kt + 32*kh + 16*ki + lm;
                #pragma unroll
                for (int qi = 0; qi < 2; ++qi) {
                    const int qq = qwB + 16*qi + 4*q4;
                    #pragma unroll
                    for (int r = 0; r < 4; ++r)
                        if (key > qq + r) sB[qi][ki][r] = -INFINITY;
                }
            }
        }

        // ---- p = exp2(s); l accumulate; P write (per-wave LDS, no barrier) ----
        #pragma unroll
        for (int qi = 0; qi < 2; ++qi)
            #pragma unroll
            for (int ki = 0; ki < 2; ++ki)
                #pragma unroll
                for (int r = 0; r < 4; ++r) {
                    const float pb = EXP2(sB[qi][ki][r]);
                    lB[qi][r] += pb;
                    pwaB[qi*640 + r*40 + ki*16] = f2bf_fast(pb);
                }

        if (doA) {
            if (kt + 32*kh + 31 > qwA) {
                #pragma unroll
                for (int ki = 0; ki < 2; ++ki) {
                    const int key = kt + 32*kh + 16*ki + lm;
                    #pragma unroll
                    for (int qi = 0; qi < 2; ++qi) {
                        const int qq = qwA + 16*qi + 4*q4;
                        #pragma unroll
                        for (int r = 0; r < 4; ++r)
                            if (key > qq + r) sA[qi][ki][r] = -INFINITY;
                    }
                }
            }
            #pragma unroll
            for (int qi = 0; qi < 2; ++qi)
                #pragma unroll
                for (int ki = 0; ki < 2; ++ki)
                    #pragma unroll
                    for (int r = 0; r < 4; ++r) {
                        const float pa = EXP2(sA[qi][ki][r]);
                        lA[qi][r] += pa;
                        pwaA[qi*640 + r*40 + ki*16] = f2bf_fast(pa);
                    }
        }

        // ---- O += P V for both streams ----
        {
            bf16x8 paB[2];
            paB[0] = *(const bf16x8*)(parB);
            paB[1] = *(const bf16x8*)(parB + 640);
            #pragma unroll
            for (int dc = 0; dc < 4; ++dc)
                #pragma unroll
                for (int qi = 0; qi < 2; ++qi)
                    oB[qi][dc] = mfma16(paB[qi], bv[dc], oB[qi][dc]);
        }
        if (doA) {
            bf16x8 paA[2];
            paA[0] = *(const bf16x8*)(parA);
            paA[1] = *(const bf16x8*)(parA + 640);
            #pragma unroll
            for (int dc = 0; dc < 4; ++dc)
                #pragma unroll
                for (int qi = 0; qi < 2; ++qi)
                    oA[qi][dc] = mfma16(paA[qi], bv[dc], oA[qi][dc]);
        }

        kc += 4096; vc += 4096;
        bk[0][0] = nk[0][0]; bk[0][1] = nk[0][1];
        bk[1][0] = nk[1][0]; bk[1][1] = nk[1][1];
    }

    // ---- l reduction over the key axis within the wave (lm groups) ----
    #pragma unroll
    for (int qi = 0; qi < 2; ++qi)
        #pragma unroll
        for (int r = 0; r < 4; ++r) {
            float a = lA[qi][r], b = lB[qi][r];
            #pragma unroll
            for (int mk = 1; mk <= 8; mk <<= 1) {
                a += __shfl_xor(a, mk);
                b += __shfl_xor(b, mk);
            }
            lA[qi][r] = a; lB[qi][r] = b;
        }

    // ---- cross-wave (key-half) reduction: stream A, then stream B ----
    if (kh == 1) {
        #pragma unroll
        for (int qi = 0; qi < 2; ++qi)
            #pragma unroll
            for (int r = 0; r < 4; ++r) {
                const int qq = 16*qi + 4*q4 + r;
                #pragma unroll
                for (int dc = 0; dc < 4; ++dc)
                    Ox[qh][qq][16*dc + lm] = oA[qi][dc][r];
                if (lm == 0) Lx[qh][qq] = lA[qi][r];
            }
    }
    __syncthreads();
    if (kh == 0) {
        #pragma unroll
        for (int qi = 0; qi < 2; ++qi)
            #pragma unroll
            for (int r = 0; r < 4; ++r) {
                const int qq = 16*qi + 4*q4 + r;
                const float inv = 1.f / (lA[qi][r] + Lx[qh][qq]);
                const size_t row = (size_t)(qwA + qq) * DIM + (h << 6) + lm;
                #pragma unroll
                for (int dc = 0; dc < 4; ++dc) {
                    const float v = oA[qi][dc][r] + Ox[qh][qq][16*dc + lm];
                    Attn[row + 16*dc] = f2bf(v * inv);
                }
            }
    }
    __syncthreads();
    if (kh == 1) {
        #pragma unroll
        for (int qi = 0; qi < 2; ++qi)
            #pragma unroll
            for (int r = 0; r < 4; ++r) {
                const int qq = 16*qi + 4*q4 + r;
                #pragma unroll
                for (int dc = 0; dc < 4; ++dc)
                    Ox[qh][qq][16*dc + lm] = oB[qi][dc][r];
                if (lm == 0) Lx[qh][qq] = lB[qi][r];
            }
    }
    __syncthreads();
    if (kh == 0) {
        #pragma unroll
        for (int qi = 0; qi < 2; ++qi)
            #pragma unroll
            for (int r = 0; r < 4; ++r) {
                const int qq = 16*qi + 4*q4 + r;
                const float inv = 1.f / (lB[qi][r] + Lx[qh][qq]);
                const size_t row = (size_t)(qwB + qq) * DIM + (h << 6) + lm;
                #pragma unroll
                for (int dc = 0; dc < 4; ++dc) {
                    const float v = oB[qi][dc][r] + Ox[qh][qq][16*dc + lm];
                    Attn[row + 16*dc] = f2bf(v * inv);
                }
            }
    }
}

// ---------------------------------------------------------------------------
// Kernel 3: out projection — BK 32 -> 64 (new): halve the barrier count.
// out's loop is the 2-phase stage->sync(+vmcnt drain)->compute pattern with
// the worst MFMA:ds ratio of our GEMMs (8:6); the per-barrier drain is the
// exposed cost (m233: ~72% of 2-phase time is stage+drain+barrier).  BK=64
// duplicates the PROVEN BK=32 buffer layout per k-half (same 64B row
// stride, no new bank-conflict pattern, gload dest stays linear), giving
// 16 MFMA per barrier interval over 16 iterations instead of 8 over 32.
// LDS 24 KB -> 48 KB: still >= 2 blocks/CU (grid caps residency at 2).
// ---------------------------------------------------------------------------
__global__ __launch_bounds__(256)
void out_mfma_kernel(const unsigned short* __restrict__ Ab,
                     const void* __restrict__ Wo_, const unsigned short* __restrict__ Wc,
                     const int* __restrict__ flag,
                     void* __restrict__ Out)
{
    __shared__ unsigned short As[2][2][4096];   // 32 KB: [buf][khalf][128 rows x 32]
    __shared__ unsigned short Bs[2][2][2048];   // 16 KB: [buf][khalf][64 rows x 32]

    const int isf32 = *flag;
    const unsigned short* Wb = isf32 ? Wc : (const unsigned short*)Wo_;

    const int tid  = threadIdx.x;
    const int lane = tid & 63;
    const int wave = tid >> 6;
    const int lm = lane & 15, q4 = lane >> 4;
    const int rbase = blockIdx.y * 128;
    const int cbase = blockIdx.x * 64;

    const int srow16 = lane >> 2;
    const int scol = (lane & 3) * 8;

    const unsigned short* asrc = Ab + (size_t)(rbase + wave*32 + srow16) * DIM + scol;
    const unsigned short* bsrc = Wb + (size_t)(cbase + wave*16 + srow16) * DIM + scol;
    const int la = (wave*32 + lm)*32 + q4*8;
    const int lb = lm*32 + q4*8;

    f32x4 acc[2][4];
    #pragma unroll
    for (int i = 0; i < 2; ++i)
        #pragma unroll
        for (int j = 0; j < 4; ++j) acc[i][j] = (f32x4){0.f, 0.f, 0.f, 0.f};

    #define OSTAGE(buf)                                                              \
        {                                                                             \
            _Pragma("unroll")                                                         \
            for (int kk = 0; kk < 2; ++kk) {                                          \
                _Pragma("unroll")                                                     \
                for (int j = 0; j < 2; ++j)                                           \
                    gload_lds16(asrc + (size_t)j*16*DIM + kk*32,                      \
                                &As[buf][kk][(wave*32 + j*16)*32]);                   \
                gload_lds16(bsrc + kk*32, &Bs[buf][kk][(wave*16)*32]);                \
            }                                                                         \
            asrc += 64; bsrc += 64;                                                   \
        }

    OSTAGE(0)
    for (int it = 0; it < DIM/64; ++it) {
        const int cur = it & 1;
        __syncthreads();
        if (it + 1 < DIM/64) OSTAGE(cur ^ 1)

        bf16x8 a[2][2], b[2][4];
        #pragma unroll
        for (int kk = 0; kk < 2; ++kk) {
            #pragma unroll
            for (int mi = 0; mi < 2; ++mi)
                a[kk][mi] = *(const bf16x8*)&As[cur][kk][la + mi*512];
            #pragma unroll
            for (int ni = 0; ni < 4; ++ni)
                b[kk][ni] = *(const bf16x8*)&Bs[cur][kk][lb + ni*512];
        }
        #pragma unroll
        for (int kk = 0; kk < 2; ++kk)
            #pragma unroll
            for (int mi = 0; mi < 2; ++mi)
                #pragma unroll
                for (int ni = 0; ni < 4; ++ni)
                    acc[mi][ni] = mfma16(a[kk][mi], b[kk][ni], acc[mi][ni]);
    }
    #undef OSTAGE

    #pragma unroll
    for (int mi = 0; mi < 2; ++mi)
        #pragma unroll
        for (int r = 0; r < 4; ++r) {
            const size_t n = rbase + wave*32 + mi*16 + q4*4 + r;
            #pragma unroll
            for (int ni = 0; ni < 4; ++ni) {
                const size_t e = cbase + ni*16 + lm;
                const float v = acc[mi][ni][r];
                if (isf32) ((float*)Out)[n * DIM + e] = v;
                else       ((unsigned short*)Out)[n * DIM + e] = f2bf(v);
            }
        }
}

// ---------------------------------------------------------------------------
extern "C" void kernel_launch(void* const* d_in, const int* in_sizes, int n_in,
                              void* d_out, int out_size, void* d_ws, size_t ws_size,
                              hipStream_t stream) {
    const void* X    = d_in[0];
    const void* Wqkv = d_in[1];
    const void* Wout = d_in[2];

    int* flag = (int*)d_ws;
    unsigned short* base = (unsigned short*)((char*)d_ws + 256);
    const size_t nX = (size_t)N_SEQ * DIM;
    const size_t nWq = (size_t)E3 * DIM;
    const size_t nWo = (size_t)DIM * DIM;
    unsigned short* Xb  = base;
    unsigned short* Wqb = Xb + nX;
    unsigned short* Wob = Wqb + nWq;
    unsigned short* Qf  = Wob + nWo;
    unsigned short* Kf  = Qf + nX;
    unsigned short* Vf  = Kf + nX;
    unsigned short* At  = Vf + nX;
    float4* Rt = (float4*)(At + nX);     // RoPE table: 4096*16 float4 = 1 MB

    prep_kernel<<<768, 256, 0, stream>>>(X, Wqkv, Wout, Xb, Wqb, Wob, Rt, flag);
    qkv_mfma_kernel<<<dim3(E3 / 128, N_SEQ / 128), 256, 0, stream>>>(X, Xb, Wqkv, Wqb, flag, Rt, Qf, Kf, Vf);
    attn_mfma_kernel<<<dim3(NHEAD * 32), 256, 0, stream>>>(Qf, Kf, Vf, At);
    out_mfma_kernel<<<dim3(DIM / 64, N_SEQ / 128), 256, 0, stream>>>(At, Wout, Wob, flag, d_out);
}